// Round 11
// baseline (73.174 us; speedup 1.0000x reference)
//
#include <hip/hip_runtime.h>
#include <math.h>
#include <stdint.h>

// NoisyTopKGating: B=4, S=4096, D=2048, E=64, K=2
#define D_ 2048
#define E_ 64
#define T_ 16384

#define BM 32                 // tokens per block
#define BK 32                 // k per tile
#define KTILES 64             // D_/BK
#define ABUF_B 4096           // 32 rows x 128 B (f32 x-tile)
#define BBUF_B 16384          // 16 frag-rows x 1024 B (2-plane f16 W tile)
#define BUF_B (ABUF_B + BBUF_B)   // 20480 per buffer
#define NBUF 3                // triple buffer: 2 tiles in flight
#define CT_STRIDE 132         // fp32 C tile stride (epilogue)

typedef _Float16 h8 __attribute__((ext_vector_type(8)));   // 8 f16 (4 VGPR)
typedef float f4v __attribute__((ext_vector_type(4)));     // MFMA acc

// in-register 2-plane f16 split: x = h + m/1024 (m scaled into normal range)
__device__ __forceinline__ void split2(const float4& a, const float4& b,
                                       h8& h, h8& m) {
    const float xe[8] = {a.x, a.y, a.z, a.w, b.x, b.y, b.z, b.w};
#pragma unroll
    for (int i = 0; i < 8; ++i) {
        const _Float16 hh_ = (_Float16)xe[i];              // v_cvt_f16_f32 (RNE)
        const float r = (xe[i] - (float)hh_) * 1024.0f;
        h[i] = hh_;
        m[i] = (_Float16)r;
    }
}

// async global->LDS DMA, 16 B per lane
__device__ __forceinline__ void gload16(const void* g, void* l) {
    __builtin_amdgcn_global_load_lds(
        (const __attribute__((address_space(1))) uint32_t*)g,
        (__attribute__((address_space(3))) uint32_t*)l, 16, 0, 0);
}

// ================= per-token noisy top-2 epilogue (shared) ==================
__device__ __forceinline__ void topk_epilogue(float g, float nl, float nz,
                                              int lane, size_t tg,
                                              float* __restrict__ out_probs,
                                              float* __restrict__ out_idx) {
    // softplus(z) = max(z,0) + log1p(exp(-|z|))
    const float sp = fmaxf(nl, 0.f) + log1pf(expf(-fabsf(nl)));
    const float noisy = g + nz * sp;

    float v = noisy;
    int idx = lane;
#pragma unroll
    for (int off = 32; off > 0; off >>= 1) {
        const float ov = __shfl_xor(v, off);
        const int oi = __shfl_xor(idx, off);
        if (ov > v || (ov == v && oi < idx)) { v = ov; idx = oi; }
    }
    const float v1 = v;
    const int i1 = idx;
    v = (lane == i1) ? -INFINITY : noisy;
    idx = lane;
#pragma unroll
    for (int off = 32; off > 0; off >>= 1) {
        const float ov = __shfl_xor(v, off);
        const int oi = __shfl_xor(idx, off);
        if (ov > v || (ov == v && oi < idx)) { v = ov; idx = oi; }
    }
    const float v2 = v;
    const int i2 = idx;

    const float e2 = expf(v2 - v1);
    const float denom = 1.f + e2;
    const float p = (lane == i1) ? (1.f / denom)
                                 : ((lane == i2) ? (e2 / denom) : 0.f);
    out_probs[tg * E_ + lane] = p;
    if (lane == 0) {
        out_idx[tg * 2 + 0] = (float)i1;
        out_idx[tg * 2 + 1] = (float)i2;
    }
}

// ---------------- kernel 1: pre-split W = [Wg;Wn] into 2 f16 planes --------
// Frag-linear layout: plane p (mid scaled x1024), frag f(8), k-step s(64),
// lane(64) -> 8 f16.  n = f*16 + (lane&15), k = s*32 + (lane>>4)*8 + i.
__global__ void w_split_kernel(const float* __restrict__ Wg,
                               const float* __restrict__ Wn,
                               h8* __restrict__ wsp) {
    const int idx = blockIdx.x * blockDim.x + threadIdx.x;  // 0..32767
    const int lane = idx & 63;
    const int s = (idx >> 6) & 63;
    const int f = idx >> 12;
    const int n = f * 16 + (lane & 15);
    const int k0 = s * 32 + ((lane >> 4) << 3);
    const float* src = (n < 64) ? &Wg[(size_t)n * D_ + k0]
                                : &Wn[(size_t)(n - 64) * D_ + k0];
    h8 hv, mv;
#pragma unroll
    for (int i = 0; i < 8; ++i) {
        const float w = src[i];
        const _Float16 wh = (_Float16)w;
        const float r = (w - (float)wh) * 1024.0f;
        hv[i] = wh;
        mv[i] = (_Float16)r;
    }
    wsp[0 * 32768 + idx] = hv;
    wsp[1 * 32768 + idx] = mv;
}

// ---------------- kernel 2: fused split-f16 MFMA GEMM + noisy top-2 --------
// BM=32, 512 threads = 8 waves (2m x 4n), grid=512 -> 2 blocks/CU.
// Triple-buffered LDS, DMA staged 2 tiles ahead, counted vmcnt at a raw
// s_barrier (T4: never drain to 0 in the main loop).
// 4 scaled f16 products in 4 acc chains: c = hh + (hm+mh)/1024 + mm/2^20.
__launch_bounds__(512)
__global__ void gemm_topk_kernel(const float* __restrict__ x,
                                 const h8* __restrict__ wsp,
                                 const float* __restrict__ bg,
                                 const float* __restrict__ bn,
                                 const float* __restrict__ noise,
                                 float* __restrict__ out_probs,
                                 float* __restrict__ out_idx) {
    __shared__ __align__(16) char smem[NBUF * BUF_B];  // 61440 B
    const int tid = threadIdx.x;
    const int lane = tid & 63;
    const int wv = tid >> 6;           // 0..7
    const int wm = wv >> 2;            // 0..1 (m half: 16 rows)
    const int wn = wv & 3;             // 0..3 (n quadrant: 32 cols)
    const int block_m0 = blockIdx.x * BM;

    const int arow = lane & 15;
    const int akg = lane >> 4;
    const char* wb = (const char*)wsp;

    f4v hh0{}, hh1{}, hm0{}, hm1{}, mh0{}, mh1{}, mm0{}, mm1{};

    // A staging: threads 0..255 (waves 0-3), row=tid>>3, chunk slot=tid&7;
    // source chunk pre-swizzled (c ^ (row&7)) so reads XOR the same (rule #21).
    const int sar = tid >> 3;
    const int sac = tid & 7;
    const float* sasrc = x + (size_t)(block_m0 + sar) * D_ + ((sac ^ (sar & 7)) << 2);
    const int blv = lane;

    auto STAGE = [&](int t, int b) {
        char* base = smem + b * BUF_B;
        if (tid < 256)                                     // waves 0-3: 3 loads
            gload16(sasrc + t * BK, base + tid * 16);
        gload16(wb + ((size_t)(0 * 32768 + wv * 4096 + t * 64 + blv)) * 16,
                base + ABUF_B + ((0 * 8 + wv) * 64 + blv) * 16);
        gload16(wb + ((size_t)(1 * 32768 + wv * 4096 + t * 64 + blv)) * 16,
                base + ABUF_B + ((1 * 8 + wv) * 64 + blv) * 16);
    };

    auto COMPUTE = [&](int b) {
        const char* base = smem + b * BUF_B;
        const int r = wm * 16 + arow;
        const int swz = r & 7;
        const float4 f0 = *(const float4*)(base + r * 128 + (((akg * 2 + 0) ^ swz) << 4));
        const float4 f1 = *(const float4*)(base + r * 128 + (((akg * 2 + 1) ^ swz) << 4));
        h8 xh, xm;
        split2(f0, f1, xh, xm);
        const char* Bb = base + ABUF_B;
        const int fA = wn * 2, fB = wn * 2 + 1;
        const h8 bh0 = *(const h8*)(Bb + (fA * 64 + lane) * 16);
        const h8 bh1 = *(const h8*)(Bb + (fB * 64 + lane) * 16);
        const h8 bm0 = *(const h8*)(Bb + ((8 + fA) * 64 + lane) * 16);
        const h8 bm1 = *(const h8*)(Bb + ((8 + fB) * 64 + lane) * 16);
#define MF(A, B, C) C = __builtin_amdgcn_mfma_f32_16x16x32_f16(A, B, C, 0, 0, 0)
        MF(xh, bh0, hh0); MF(xh, bh1, hh1);
        MF(xh, bm0, hm0); MF(xh, bm1, hm1);
        MF(xm, bh0, mh0); MF(xm, bh1, mh1);
        MF(xm, bm0, mm0); MF(xm, bm1, mm1);
#undef MF
    };

    // ---- main loop: 2 tiles of DMA in flight; counted vmcnt at barrier ----
    STAGE(0, 0);
    STAGE(1, 1);
#pragma unroll 1
    for (int t = 0; t < KTILES; ++t) {
        // Wait for tile t's DMA (leave tile t+1's in flight), then barrier so
        // every wave sees every wave's tile-t data. vmcnt(N) N = loads of the
        // newest stage: 3 for waves 0-3 (A+2B), 2 for waves 4-7 (2B).
        if (t < KTILES - 1) {
            if (wv < 4) asm volatile("s_waitcnt vmcnt(3)" ::: "memory");
            else        asm volatile("s_waitcnt vmcnt(2)" ::: "memory");
        } else {
            asm volatile("s_waitcnt vmcnt(0)" ::: "memory");
        }
        __builtin_amdgcn_s_barrier();
        __builtin_amdgcn_sched_barrier(0);
        if (t + 2 < KTILES) STAGE(t + 2, (t + 2) % NBUF);  // writes buf last
                                                           // read in t-1 (sealed
                                                           // by this barrier)
        COMPUTE(t % NBUF);
    }
    __syncthreads();   // all compute done before smem is reused for Ct

    // ---- epilogue: combine scaled acc chains, C to LDS, noisy top-2 ----
    float* Ct = (float*)smem;  // [32][CT_STRIDE] = 16896 B
    {
        const float S1 = 1.0f / 1024.0f;
        const float S2 = S1 * S1;
        const int ko4 = akg * 4;
#pragma unroll
        for (int r = 0; r < 4; ++r) {
            const int row = wm * 16 + ko4 + r;
            const int col0 = (wn * 2 + 0) * 16 + arow;
            const int col1 = (wn * 2 + 1) * 16 + arow;
            Ct[row * CT_STRIDE + col0] = hh0[r] + (hm0[r] + mh0[r]) * S1 + mm0[r] * S2;
            Ct[row * CT_STRIDE + col1] = hh1[r] + (hm1[r] + mh1[r]) * S1 + mm1[r] * S2;
        }
    }
    __syncthreads();

    const float my_bg = bg[lane];
    const float my_bn = bn[lane];
#pragma unroll 1
    for (int tt = 0; tt < 4; ++tt) {
        const int tl = wv * 4 + tt;
        const size_t tg = (size_t)block_m0 + tl;
        const float g = Ct[tl * CT_STRIDE + lane] + my_bg;
        const float nl = Ct[tl * CT_STRIDE + 64 + lane] + my_bn;
        const float nz = noise[tg * E_ + lane];
        topk_epilogue(g, nl, nz, lane, tg, out_probs, out_idx);
    }
}

// ---------------- fallback: pure-f32 fused kernel (no ws) -------------------
#define FBM 64
#define FBK 32
#define XS_STRIDE 68
#define WS_STRIDE 132
#define FCT_STRIDE 132

__launch_bounds__(256)
__global__ void noisy_topk_f32_kernel(const float* __restrict__ x,
                                      const float* __restrict__ Wg,
                                      const float* __restrict__ bg,
                                      const float* __restrict__ Wn,
                                      const float* __restrict__ bn,
                                      const float* __restrict__ noise,
                                      float* __restrict__ out_probs,
                                      float* __restrict__ out_idx) {
    __shared__ float smem[FBM * FCT_STRIDE];
    float* Xs = smem;
    float* Ws = smem + FBK * XS_STRIDE;

    const int tid = threadIdx.x;
    const int block_m0 = blockIdx.x * FBM;
    const int n0 = (tid & 31) * 4;
    const int m0 = (tid >> 5) * 8;

    float acc[8][4];
#pragma unroll
    for (int i = 0; i < 8; ++i)
#pragma unroll
        for (int j = 0; j < 4; ++j) acc[i][j] = 0.f;

    const int sj = tid & 7;
    const int sr = tid >> 3;

    for (int k0 = 0; k0 < D_; k0 += FBK) {
        __syncthreads();
#pragma unroll
        for (int it = 0; it < 2; ++it) {
            const int m = sr + it * 32;
            const float4 v = *reinterpret_cast<const float4*>(
                &x[(size_t)(block_m0 + m) * D_ + k0 + 4 * sj]);
            Xs[(4 * sj + 0) * XS_STRIDE + m] = v.x;
            Xs[(4 * sj + 1) * XS_STRIDE + m] = v.y;
            Xs[(4 * sj + 2) * XS_STRIDE + m] = v.z;
            Xs[(4 * sj + 3) * XS_STRIDE + m] = v.w;
        }
#pragma unroll
        for (int it = 0; it < 4; ++it) {
            const int n = sr + it * 32;
            const float* wrow = (n < 64) ? &Wg[(size_t)n * D_] : &Wn[(size_t)(n - 64) * D_];
            const float4 v = *reinterpret_cast<const float4*>(&wrow[k0 + 4 * sj]);
            Ws[(4 * sj + 0) * WS_STRIDE + n] = v.x;
            Ws[(4 * sj + 1) * WS_STRIDE + n] = v.y;
            Ws[(4 * sj + 2) * WS_STRIDE + n] = v.z;
            Ws[(4 * sj + 3) * WS_STRIDE + n] = v.w;
        }
        __syncthreads();
#pragma unroll
        for (int k = 0; k < FBK; ++k) {
            const float4 a0 = *reinterpret_cast<const float4*>(&Xs[k * XS_STRIDE + m0]);
            const float4 a1 = *reinterpret_cast<const float4*>(&Xs[k * XS_STRIDE + m0 + 4]);
            const float4 b4 = *reinterpret_cast<const float4*>(&Ws[k * WS_STRIDE + n0]);
            const float am[8] = {a0.x, a0.y, a0.z, a0.w, a1.x, a1.y, a1.z, a1.w};
            const float bb[4] = {b4.x, b4.y, b4.z, b4.w};
#pragma unroll
            for (int i = 0; i < 8; ++i)
#pragma unroll
                for (int j = 0; j < 4; ++j)
                    acc[i][j] = fmaf(am[i], bb[j], acc[i][j]);
        }
    }

    __syncthreads();
    float* Ct = smem;
#pragma unroll
    for (int i = 0; i < 8; ++i)
#pragma unroll
        for (int j = 0; j < 4; ++j)
            Ct[(m0 + i) * FCT_STRIDE + n0 + j] = acc[i][j];
    __syncthreads();

    const int wave = tid >> 6;
    const int lane = tid & 63;
    const float my_bg = bg[lane];
    const float my_bn = bn[lane];
#pragma unroll 1
    for (int tt = 0; tt < 16; ++tt) {
        const int tl = wave * 16 + tt;
        const size_t tg = (size_t)block_m0 + tl;
        const float g = Ct[tl * FCT_STRIDE + lane] + my_bg;
        const float nl = Ct[tl * FCT_STRIDE + 64 + lane] + my_bn;
        const float nz = noise[tg * E_ + lane];
        topk_epilogue(g, nl, nz, lane, tg, out_probs, out_idx);
    }
}

extern "C" void kernel_launch(void* const* d_in, const int* in_sizes, int n_in,
                              void* d_out, int out_size, void* d_ws, size_t ws_size,
                              hipStream_t stream) {
    const float* x = (const float*)d_in[0];
    const float* Wg = (const float*)d_in[1];
    const float* bg = (const float*)d_in[2];
    const float* Wn = (const float*)d_in[3];
    const float* bn = (const float*)d_in[4];
    const float* noise = (const float*)d_in[5];
    float* out_probs = (float*)d_out;
    float* out_idx = out_probs + (size_t)T_ * E_;

    const size_t WSP_BYTES = (size_t)2 * 32768 * 16;  // 1.0 MB
    if (ws_size >= WSP_BYTES) {
        h8* wsp = (h8*)d_ws;
        hipLaunchKernelGGL(w_split_kernel, dim3(128), dim3(256), 0, stream, Wg, Wn, wsp);
        hipLaunchKernelGGL(gemm_topk_kernel, dim3(T_ / BM), dim3(512), 0, stream,
                           x, wsp, bg, bn, noise, out_probs, out_idx);
    } else {
        hipLaunchKernelGGL(noisy_topk_f32_kernel, dim3(T_ / FBM), dim3(256), 0, stream,
                           x, Wg, bg, Wn, bn, noise, out_probs, out_idx);
    }
}

// Round 12
// 59.616 us; speedup vs baseline: 1.2274x; 1.2274x over previous
//
#include <hip/hip_runtime.h>
#include <math.h>
#include <stdint.h>

// NoisyTopKGating: B=4, S=4096, D=2048, E=64, K=2
#define D_ 2048
#define E_ 64
#define T_ 16384

#define BM 64                 // tokens per block
#define BK 64                 // k per tile
#define KTILES 32             // D_/BK
#define ABUF_B 16384          // A: 2 planes x 4 mfrag x 2 ks x 64 lanes x 16 B
#define BBUF_B 32768          // B: 2 planes x 8 frag x 2 ks x 64 lanes x 16 B
#define BUF_B (ABUF_B + BBUF_B)   // 48 KB per buffer
#define CT_STRIDE 132         // fp32 C tile stride (epilogue)

typedef _Float16 h8 __attribute__((ext_vector_type(8)));   // 8 f16 (4 VGPR)
typedef float f4v __attribute__((ext_vector_type(4)));     // MFMA acc

// in-register 2-plane f16 split: x = h + m/1024 (m scaled into normal range)
__device__ __forceinline__ void split2(const float4& a, const float4& b,
                                       h8& h, h8& m) {
    const float xe[8] = {a.x, a.y, a.z, a.w, b.x, b.y, b.z, b.w};
#pragma unroll
    for (int i = 0; i < 8; ++i) {
        const _Float16 hh_ = (_Float16)xe[i];              // v_cvt_f16_f32 (RNE)
        const float r = (xe[i] - (float)hh_) * 1024.0f;
        h[i] = hh_;
        m[i] = (_Float16)r;
    }
}

// async global->LDS DMA, 16 B per lane (dest = wave-uniform base + lane*16)
__device__ __forceinline__ void gload16(const void* g, void* l) {
    __builtin_amdgcn_global_load_lds(
        (const __attribute__((address_space(1))) uint32_t*)g,
        (__attribute__((address_space(3))) uint32_t*)l, 16, 0, 0);
}

// ================= per-token noisy top-2 epilogue (shared) ==================
__device__ __forceinline__ void topk_epilogue(float g, float nl, float nz,
                                              int lane, size_t tg,
                                              float* __restrict__ out_probs,
                                              float* __restrict__ out_idx) {
    // softplus(z) = max(z,0) + log1p(exp(-|z|))
    const float sp = fmaxf(nl, 0.f) + log1pf(expf(-fabsf(nl)));
    const float noisy = g + nz * sp;

    float v = noisy;
    int idx = lane;
#pragma unroll
    for (int off = 32; off > 0; off >>= 1) {
        const float ov = __shfl_xor(v, off);
        const int oi = __shfl_xor(idx, off);
        if (ov > v || (ov == v && oi < idx)) { v = ov; idx = oi; }
    }
    const float v1 = v;
    const int i1 = idx;
    v = (lane == i1) ? -INFINITY : noisy;
    idx = lane;
#pragma unroll
    for (int off = 32; off > 0; off >>= 1) {
        const float ov = __shfl_xor(v, off);
        const int oi = __shfl_xor(idx, off);
        if (ov > v || (ov == v && oi < idx)) { v = ov; idx = oi; }
    }
    const float v2 = v;
    const int i2 = idx;

    const float e2 = expf(v2 - v1);
    const float denom = 1.f + e2;
    const float p = (lane == i1) ? (1.f / denom)
                                 : ((lane == i2) ? (e2 / denom) : 0.f);
    out_probs[tg * E_ + lane] = p;
    if (lane == 0) {
        out_idx[tg * 2 + 0] = (float)i1;
        out_idx[tg * 2 + 1] = (float)i2;
    }
}

// ---------------- kernel 1: pre-split W = [Wg;Wn] into 2 f16 planes --------
// Frag-linear: plane p (mid scaled x1024), frag f(8), k-step s(64), lane(64).
// n = f*16 + (lane&15), k = s*32 + (lane>>4)*8 + i.
__global__ void w_split_kernel(const float* __restrict__ Wg,
                               const float* __restrict__ Wn,
                               h8* __restrict__ wsp) {
    const int idx = blockIdx.x * blockDim.x + threadIdx.x;  // 0..32767
    const int lane = idx & 63;
    const int s = (idx >> 6) & 63;
    const int f = idx >> 12;
    const int n = f * 16 + (lane & 15);
    const int k0 = s * 32 + ((lane >> 4) << 3);
    const float* src = (n < 64) ? &Wg[(size_t)n * D_ + k0]
                                : &Wn[(size_t)(n - 64) * D_ + k0];
    h8 hv, mv;
#pragma unroll
    for (int i = 0; i < 8; ++i) {
        const float w = src[i];
        const _Float16 wh = (_Float16)w;
        const float r = (w - (float)wh) * 1024.0f;
        hv[i] = wh;
        mv[i] = (_Float16)r;
    }
    wsp[0 * 32768 + idx] = hv;
    wsp[1 * 32768 + idx] = mv;
}

// ---------------- kernel 2: fused split-f16 MFMA GEMM + noisy top-2 --------
// BM=64, BK=64, 512 threads = 8 waves (2m x 4n), grid=256.
// A: reg-staged (T14 issue-early/split+write-late) into frag-linear f16 LDS.
// B: DMA global_load_lds from frag-linear ws. Double buffer, 1 barrier/tile.
// 3 scaled acc chains: logit = hh + cx/2^10 + mm/2^20.
__launch_bounds__(512)
__global__ void gemm_topk_kernel(const float* __restrict__ x,
                                 const h8* __restrict__ wsp,
                                 const float* __restrict__ bg,
                                 const float* __restrict__ bn,
                                 const float* __restrict__ noise,
                                 float* __restrict__ out_probs,
                                 float* __restrict__ out_idx) {
    __shared__ __align__(16) char smem[2 * BUF_B];  // 96 KB
    const int tid = threadIdx.x;
    const int lane = tid & 63;
    const int wv = tid >> 6;           // 0..7
    const int wm = wv >> 2;            // 0..1 (m half: 32 rows)
    const int wn = wv & 3;             // 0..3 (n quadrant: 32 cols)
    const int block_m0 = blockIdx.x * BM;
    const char* wb = (const char*)wsp;

    // A staging ownership: thread -> (sfrag, sks, sl); source row/chunk derived
    const int sfrag = tid >> 7;        // 0..3 (16-row group)
    const int sks = (tid >> 6) & 1;    // k-step within tile
    const int sl = tid & 63;           // frag lane
    const int srow = sfrag * 16 + (sl & 15);
    const int schunk = sks * 4 + (sl >> 4);          // 8-float chunk 0..7
    const float* asrc = x + (size_t)(block_m0 + srow) * D_ + schunk * 8;
    const int aw_hi = ((0 * 4 + sfrag) * 2 + sks) * 1024 + sl * 16;
    const int aw_mid = ((1 * 4 + sfrag) * 2 + sks) * 1024 + sl * 16;

    f4v hh[2][2] = {}, cx[2][2] = {}, mm[2][2] = {};   // [mi][nf]

    auto STAGE_B = [&](int t, int b) {
        char* Bb = smem + b * BUF_B + ABUF_B;
#pragma unroll
        for (int p = 0; p < 2; ++p)
#pragma unroll
            for (int ks = 0; ks < 2; ++ks)
                gload16(wb + ((size_t)(p * 32768 + wv * 4096 + (t * 2 + ks) * 64 + lane)) * 16,
                        Bb + ((p * 8 + wv) * 2 + ks) * 1024 + lane * 16);
    };
    auto ALOAD = [&](int t, float4& ra, float4& rb) {
        ra = *(const float4*)(asrc + t * BK);
        rb = *(const float4*)(asrc + t * BK + 4);
    };
    auto ASPLIT = [&](const float4& ra, const float4& rb, int b) {
        h8 hv, mv;
        split2(ra, rb, hv, mv);
        char* Ab = smem + b * BUF_B;
        *(h8*)(Ab + aw_hi) = hv;
        *(h8*)(Ab + aw_mid) = mv;
    };
    auto COMPUTE = [&](int b) {
        const char* Ab = smem + b * BUF_B;
        const char* Bb = Ab + ABUF_B;
#pragma unroll
        for (int ks = 0; ks < 2; ++ks) {
            h8 ah[2], am[2], bh[2], bm[2];
#pragma unroll
            for (int mi = 0; mi < 2; ++mi) {
                const int mf = wm * 2 + mi;
                ah[mi] = *(const h8*)(Ab + ((0 * 4 + mf) * 2 + ks) * 1024 + lane * 16);
                am[mi] = *(const h8*)(Ab + ((1 * 4 + mf) * 2 + ks) * 1024 + lane * 16);
            }
#pragma unroll
            for (int nf = 0; nf < 2; ++nf) {
                const int f = wn * 2 + nf;
                bh[nf] = *(const h8*)(Bb + ((0 * 8 + f) * 2 + ks) * 1024 + lane * 16);
                bm[nf] = *(const h8*)(Bb + ((1 * 8 + f) * 2 + ks) * 1024 + lane * 16);
            }
#define MF(A, B, C) C = __builtin_amdgcn_mfma_f32_16x16x32_f16(A, B, C, 0, 0, 0)
#pragma unroll
            for (int mi = 0; mi < 2; ++mi)
#pragma unroll
                for (int nf = 0; nf < 2; ++nf) {
                    MF(ah[mi], bh[nf], hh[mi][nf]);
                    MF(ah[mi], bm[nf], cx[mi][nf]);
                    MF(am[mi], bh[nf], cx[mi][nf]);
                    MF(am[mi], bm[nf], mm[mi][nf]);
                }
#undef MF
        }
    };

    // ---- prologue ----
    float4 ra0, rb0, ra1, rb1;
    ALOAD(0, ra0, rb0);
    STAGE_B(0, 0);
    ASPLIT(ra0, rb0, 0);      // buf0 <- A(0)
    ALOAD(1, ra0, rb0);       // Ra <- x(1)
    __syncthreads();

    // ---- main loop: 2 tiles per iteration (static register sets) ----
#pragma unroll 1
    for (int i = 0; i < KTILES / 2; ++i) {
        const int t = 2 * i;
        // tile t (in buf[t&1] = buf0)
        STAGE_B(t + 1, 1);                      // DMA B(t+1) -> buf1
        if (t + 2 < KTILES) ALOAD(t + 2, ra1, rb1);
        COMPUTE(0);
        ASPLIT(ra0, rb0, 1);                    // A(t+1) -> buf1
        __syncthreads();
        // tile t+1 (in buf1)
        if (t + 2 < KTILES) STAGE_B(t + 2, 0);
        if (t + 3 < KTILES) ALOAD(t + 3, ra0, rb0);
        COMPUTE(1);
        if (t + 2 < KTILES) ASPLIT(ra1, rb1, 0);
        __syncthreads();
    }

    // ---- epilogue: combine scaled acc chains, C to LDS, noisy top-2 ----
    float* Ct = (float*)smem;  // [64][CT_STRIDE] = 33792 B
    {
        const float S1 = 1.0f / 1024.0f;
        const float S2 = S1 * S1;
        const int arow = lane & 15;
        const int ko4 = (lane >> 4) * 4;
#pragma unroll
        for (int mi = 0; mi < 2; ++mi)
#pragma unroll
            for (int nf = 0; nf < 2; ++nf) {
                const int col = wn * 32 + nf * 16 + arow;
#pragma unroll
                for (int r = 0; r < 4; ++r) {
                    const int row = wm * 32 + mi * 16 + ko4 + r;
                    Ct[row * CT_STRIDE + col] =
                        hh[mi][nf][r] + cx[mi][nf][r] * S1 + mm[mi][nf][r] * S2;
                }
            }
    }
    __syncthreads();

    const float my_bg = bg[lane];
    const float my_bn = bn[lane];
#pragma unroll 1
    for (int tt = 0; tt < 8; ++tt) {
        const int tl = wv * 8 + tt;
        const size_t tg = (size_t)block_m0 + tl;
        const float g = Ct[tl * CT_STRIDE + lane] + my_bg;
        const float nl = Ct[tl * CT_STRIDE + 64 + lane] + my_bn;
        const float nz = noise[tg * E_ + lane];
        topk_epilogue(g, nl, nz, lane, tg, out_probs, out_idx);
    }
}

// ---------------- fallback: pure-f32 fused kernel (no ws) -------------------
#define FBM 64
#define FBK 32
#define XS_STRIDE 68
#define WS_STRIDE 132
#define FCT_STRIDE 132

__launch_bounds__(256)
__global__ void noisy_topk_f32_kernel(const float* __restrict__ x,
                                      const float* __restrict__ Wg,
                                      const float* __restrict__ bg,
                                      const float* __restrict__ Wn,
                                      const float* __restrict__ bn,
                                      const float* __restrict__ noise,
                                      float* __restrict__ out_probs,
                                      float* __restrict__ out_idx) {
    __shared__ float smem[FBM * FCT_STRIDE];
    float* Xs = smem;
    float* Ws = smem + FBK * XS_STRIDE;

    const int tid = threadIdx.x;
    const int block_m0 = blockIdx.x * FBM;
    const int n0 = (tid & 31) * 4;
    const int m0 = (tid >> 5) * 8;

    float acc[8][4];
#pragma unroll
    for (int i = 0; i < 8; ++i)
#pragma unroll
        for (int j = 0; j < 4; ++j) acc[i][j] = 0.f;

    const int sj = tid & 7;
    const int sr = tid >> 3;

    for (int k0 = 0; k0 < D_; k0 += FBK) {
        __syncthreads();
#pragma unroll
        for (int it = 0; it < 2; ++it) {
            const int m = sr + it * 32;
            const float4 v = *reinterpret_cast<const float4*>(
                &x[(size_t)(block_m0 + m) * D_ + k0 + 4 * sj]);
            Xs[(4 * sj + 0) * XS_STRIDE + m] = v.x;
            Xs[(4 * sj + 1) * XS_STRIDE + m] = v.y;
            Xs[(4 * sj + 2) * XS_STRIDE + m] = v.z;
            Xs[(4 * sj + 3) * XS_STRIDE + m] = v.w;
        }
#pragma unroll
        for (int it = 0; it < 4; ++it) {
            const int n = sr + it * 32;
            const float* wrow = (n < 64) ? &Wg[(size_t)n * D_] : &Wn[(size_t)(n - 64) * D_];
            const float4 v = *reinterpret_cast<const float4*>(&wrow[k0 + 4 * sj]);
            Ws[(4 * sj + 0) * WS_STRIDE + n] = v.x;
            Ws[(4 * sj + 1) * WS_STRIDE + n] = v.y;
            Ws[(4 * sj + 2) * WS_STRIDE + n] = v.z;
            Ws[(4 * sj + 3) * WS_STRIDE + n] = v.w;
        }
        __syncthreads();
#pragma unroll
        for (int k = 0; k < FBK; ++k) {
            const float4 a0 = *reinterpret_cast<const float4*>(&Xs[k * XS_STRIDE + m0]);
            const float4 a1 = *reinterpret_cast<const float4*>(&Xs[k * XS_STRIDE + m0 + 4]);
            const float4 b4 = *reinterpret_cast<const float4*>(&Ws[k * WS_STRIDE + n0]);
            const float am[8] = {a0.x, a0.y, a0.z, a0.w, a1.x, a1.y, a1.z, a1.w};
            const float bb[4] = {b4.x, b4.y, b4.z, b4.w};
#pragma unroll
            for (int i = 0; i < 8; ++i)
#pragma unroll
                for (int j = 0; j < 4; ++j)
                    acc[i][j] = fmaf(am[i], bb[j], acc[i][j]);
        }
    }

    __syncthreads();
    float* Ct = smem;
#pragma unroll
    for (int i = 0; i < 8; ++i)
#pragma unroll
        for (int j = 0; j < 4; ++j)
            Ct[(m0 + i) * FCT_STRIDE + n0 + j] = acc[i][j];
    __syncthreads();

    const int wave = tid >> 6;
    const int lane = tid & 63;
    const float my_bg = bg[lane];
    const float my_bn = bn[lane];
#pragma unroll 1
    for (int tt = 0; tt < 16; ++tt) {
        const int tl = wave * 16 + tt;
        const size_t tg = (size_t)block_m0 + tl;
        const float g = Ct[tl * FCT_STRIDE + lane] + my_bg;
        const float nl = Ct[tl * FCT_STRIDE + 64 + lane] + my_bn;
        const float nz = noise[tg * E_ + lane];
        topk_epilogue(g, nl, nz, lane, tg, out_probs, out_idx);
    }
}

extern "C" void kernel_launch(void* const* d_in, const int* in_sizes, int n_in,
                              void* d_out, int out_size, void* d_ws, size_t ws_size,
                              hipStream_t stream) {
    const float* x = (const float*)d_in[0];
    const float* Wg = (const float*)d_in[1];
    const float* bg = (const float*)d_in[2];
    const float* Wn = (const float*)d_in[3];
    const float* bn = (const float*)d_in[4];
    const float* noise = (const float*)d_in[5];
    float* out_probs = (float*)d_out;
    float* out_idx = out_probs + (size_t)T_ * E_;

    const size_t WSP_BYTES = (size_t)2 * 32768 * 16;  // 1.0 MB
    if (ws_size >= WSP_BYTES) {
        h8* wsp = (h8*)d_ws;
        hipLaunchKernelGGL(w_split_kernel, dim3(128), dim3(256), 0, stream, Wg, Wn, wsp);
        hipLaunchKernelGGL(gemm_topk_kernel, dim3(T_ / BM), dim3(512), 0, stream,
                           x, wsp, bg, bn, noise, out_probs, out_idx);
    } else {
        hipLaunchKernelGGL(noisy_topk_f32_kernel, dim3(T_ / FBM), dim3(256), 0, stream,
                           x, Wg, bg, Wn, bn, noise, out_probs, out_idx);
    }
}